// Round 15
// baseline (1447.569 us; speedup 1.0000x reference)
//
#include <hip/hip_runtime.h>
#include <hip/hip_cooperative_groups.h>

namespace cg = cooperative_groups;

#define NB    128
#define P     512
#define PP    262144            // P*P
#define TOT   33554432          // NB*PP
#define MAX_IT 100

// d_ws layout (float offsets); ws >= 1.6GB per poison-fill evidence
#define WS_W     0              // 262144 : |1/(s.s^T)+1e-5|
#define WS_U     262144         // 65536
#define WS_V     327680         // 65536
#define WS_CP    393216         // 2*128*4*512 = 524288 col partials [buf][n][rb][512]
#define WS_ERRP  917504         // 2*512
#define WS_DONE  918528         // flag
#define WS_K16   918784         // bf16[TOT] = 16777216 float slots
#define WS_K8    17696000       // fp8[TOT]  = 8388608 float slots

typedef float f32x2 __attribute__((ext_vector_type(2)));
typedef float f32x4 __attribute__((ext_vector_type(4)));

__device__ __forceinline__ f32x2 pkfma(f32x2 a, f32x2 b, f32x2 c) {
  f32x2 d;
  asm("v_pk_fma_f32 %0, %1, %2, %3" : "=v"(d) : "v"(a), "v"(b), "v"(c));
  return d;
}

__device__ __forceinline__ float bfbits(unsigned u) {
  union { unsigned b; float f; } x; x.b = u; return x.f;
}

// Fused prep+cmat: writes C, dist, K16 (bf16), K8 (OCP e4m3), W;
// zeros u, cost, DONE.
__global__ __launch_bounds__(256)
void cmat2_kernel(const float* __restrict__ x, const float* __restrict__ y,
                  const float* __restrict__ species,
                  float* __restrict__ C, float* __restrict__ dist,
                  float* __restrict__ ws, float* __restrict__ cost) {
  __shared__ float sp[P * 8];            // 16 KB: full species matrix
  const int tid = threadIdx.x;
  for (int q = tid; q < P * 8; q += 256) sp[q] = species[q];
  __syncthreads();

  const int g = blockIdx.x * 256 + tid;  // [0, TOT/4)
  const int base = g << 2;
  const int n = base >> 18;
  const int r = base & (PP - 1);
  const int i = r >> 9, j0 = r & (P - 1);
  const float* xp = x + ((n << 9) + i) * 3;
  const float x0 = xp[0], x1 = xp[1], x2 = xp[2];
  const float* yp = y + ((n << 9) + j0) * 3;
  const float* si = sp + i * 8;

  float c[4], d[4], wv[4], kf[4];
  unsigned kk[4];
#pragma unroll
  for (int q = 0; q < 4; ++q) {
    const float* sj = sp + (j0 + q) * 8;
    float gd = 0.f;
#pragma unroll
    for (int k = 0; k < 8; ++k) gd = fmaf(si[k], sj[k], gd);
    const float w = fabsf(1.0f / gd + 1e-5f);
    wv[q] = w;
    float dx = x0 - yp[q * 3 + 0];
    float dy = x1 - yp[q * 3 + 1];
    float dz = x2 - yp[q * 3 + 2];
    dx = rintf(dx) - dx; dy = rintf(dy) - dy; dz = rintf(dz) - dz;
    const float ds = dx * dx + dy * dy + dz * dz;
    d[q] = ds;
    c[q] = ds * w;
    kf[q] = __expf(-10.f * c[q]);
    const unsigned b = __float_as_uint(kf[q]);
    kk[q] = (b + 0x7fffu + ((b >> 16) & 1u)) >> 16;   // RNE to bf16
  }

  f32x4 cv = { c[0], c[1], c[2], c[3] };
  f32x4 dv = { d[0], d[1], d[2], d[3] };
  *reinterpret_cast<f32x4*>(C + base)    = cv;
  *reinterpret_cast<f32x4*>(dist + base) = dv;

  uint2 kp;
  kp.x = kk[0] | (kk[1] << 16);
  kp.y = kk[2] | (kk[3] << 16);
  *reinterpret_cast<uint2*>((unsigned short*)(ws + WS_K16) + base) = kp;

  int k8 = __builtin_amdgcn_cvt_pk_fp8_f32(kf[0], kf[1], 0, false);
  k8     = __builtin_amdgcn_cvt_pk_fp8_f32(kf[2], kf[3], k8, true);
  reinterpret_cast<int*>((unsigned char*)(ws + WS_K8))[g] = k8;

  if (n == 0) {                                        // store W once for pi
    f32x4 wv4 = { wv[0], wv[1], wv[2], wv[3] };
    *reinterpret_cast<f32x4*>(ws + WS_W + base) = wv4;
  }

  const f32x4 z4 = { 0.f, 0.f, 0.f, 0.f };
  if (g < 16384) *reinterpret_cast<f32x4*>(ws + WS_U + (g << 2)) = z4;
  if (g < 32)    *reinterpret_cast<f32x4*>(cost + (g << 2)) = z4;
  if (g == 0)    ws[WS_DONE] = 0.f;
}

// ---- PRIMARY: coop memory-K sinkhorn — R8 bytes verbatim + DONE write.
__global__ __launch_bounds__(512, 4)
void sink_m(float* __restrict__ ws) {
  cg::grid_group grid = cg::this_grid();
  const unsigned short* Kus = (const unsigned short*)(ws + WS_K16);
  float* u    = ws + WS_U;
  float* cp   = ws + WS_CP;
  float* errP = ws + WS_ERRP;

  const int tid  = threadIdx.x;
  const int lane = tid & 63;
  const int wid  = tid >> 6;               // 0..7
  const int bid  = blockIdx.x;
  const int n    = bid >> 2;
  const int rb   = bid & 3;
  const int row0 = (n << 9) + (rb << 7);

  __shared__ float vLDS[P];
  __shared__ float cbuf[8][P];
  __shared__ float wdu[8];
  __shared__ float ebc;

  vLDS[tid] = 0.f;
  __syncthreads();

  const float logmu = logf(1.0f / 512.0f + 1e-8f);
  const float muv   = 1.0f / 512.0f + 1e-8f;

  for (int it = 0; it < MAX_IT; ++it) {
    const int buf = it & 1;
    float ev[8], colacc[8];
#pragma unroll
    for (int t = 0; t < 8; ++t) {
      ev[t] = __expf(10.f * vLDS[(lane << 3) + t]);
      colacc[t] = 0.f;
    }

    float du = 0.f;
#pragma unroll 2
    for (int r = 0; r < 16; ++r) {
      const int row = row0 + (wid << 4) + r;
      const uint4* kp = reinterpret_cast<const uint4*>(Kus + ((size_t)row << 9) + (lane << 3));
      uint4 kw = *kp;
      float k[8];
      k[0] = bfbits(kw.x << 16); k[1] = bfbits(kw.x & 0xffff0000u);
      k[2] = bfbits(kw.y << 16); k[3] = bfbits(kw.y & 0xffff0000u);
      k[4] = bfbits(kw.z << 16); k[5] = bfbits(kw.z & 0xffff0000u);
      k[6] = bfbits(kw.w << 16); k[7] = bfbits(kw.w & 0xffff0000u);
      float sA = k[0] * ev[0], sB = k[1] * ev[1];
      sA = fmaf(k[2], ev[2], sA); sB = fmaf(k[3], ev[3], sB);
      sA = fmaf(k[4], ev[4], sA); sB = fmaf(k[5], ev[5], sB);
      sA = fmaf(k[6], ev[6], sA); sB = fmaf(k[7], ev[7], sB);
      float s = sA + sB;
#pragma unroll
      for (int o = 32; o > 0; o >>= 1) s += __shfl_xor(s, o);
      float uo = u[row];
      float un = 0.1f * (logmu - __logf(s));
      du += fabsf(un - uo);
      if (lane == 0) u[row] = un;
      float eu = __fdividef(muv, s);
#pragma unroll
      for (int t = 0; t < 8; ++t) colacc[t] = fmaf(k[t], eu, colacc[t]);
    }
#pragma unroll
    for (int t = 0; t < 8; ++t) cbuf[wid][(lane << 3) + t] = colacc[t];
    if (lane == 0) wdu[wid] = du;
    __syncthreads();

    {
      float s1 = cbuf[0][tid] + cbuf[1][tid] + cbuf[2][tid] + cbuf[3][tid]
               + cbuf[4][tid] + cbuf[5][tid] + cbuf[6][tid] + cbuf[7][tid];
      cp[(buf << 18) + (n << 11) + (rb << 9) + tid] = s1;
      if (tid == 0) {
        errP[(buf << 9) + bid] = wdu[0] + wdu[1] + wdu[2] + wdu[3]
                               + wdu[4] + wdu[5] + wdu[6] + wdu[7];
      }
    }
    grid.sync();

    {
      const float* cpb = cp + (buf << 18) + (n << 11);
      float sc = cpb[tid] + cpb[512 + tid] + cpb[1024 + tid] + cpb[1536 + tid];
      vLDS[tid] = 0.1f * (logmu - __logf(sc));
    }
    if (wid == 0) {
      float e = 0.f;
#pragma unroll
      for (int q = 0; q < 8; ++q) e += errP[(buf << 9) + lane + (q << 6)];
#pragma unroll
      for (int o = 32; o > 0; o >>= 1) e += __shfl_xor(e, o);
      if (lane == 0) ebc = e;
    }
    __syncthreads();
    if (ebc < 12.8f) break;
  }

  if (rb == 0) ws[WS_V + (n << 9) + tid] = vLDS[tid];
  if (tid == 0) ws[WS_DONE] = 1.0f;
}

// ---- RESCUE: fp8-K no-sync sinkhorn (R14 structure). 128 blocks x 1024 thr,
// one block per batch. K8 slice = 256 KB -> 4.2 MB/XCD ~ L2-resident.
// Runs only if coop sink_m never executed (DONE gate). Writes u, v.
__global__ __launch_bounds__(1024, 1)
void sink_g(float* __restrict__ ws) {
  if (ws[WS_DONE] != 0.f) return;          // uniform early exit
  const unsigned char* K8 = (const unsigned char*)(ws + WS_K8);
  float* u = ws + WS_U;

  const int tid  = threadIdx.x;
  const int lane = tid & 63;
  const int w    = tid >> 6;               // wave 0..15
  const int n    = blockIdx.x;             // batch

  __shared__ float evLDS[P];
  __shared__ float cbuf[16][P];

  if (tid < P) evLDS[tid] = 1.0f;          // v = 0
  __syncthreads();

  const float muv   = 1.0f / 512.0f + 1e-8f;
  const float logmu = logf(muv);
  const unsigned char* Kw = K8 + (((size_t)(n << 9) + (w << 5)) << 9) + (lane << 3);

  for (int it = 0; it < MAX_IT; ++it) {
    f32x2 ev2[4], ca2[4];
#pragma unroll
    for (int t = 0; t < 4; ++t) {
      ev2[t] = *reinterpret_cast<const f32x2*>(&evLDS[(lane << 3) + (t << 1)]);
      ca2[t].x = 0.f; ca2[t].y = 0.f;
    }

    for (int rr = 0; rr < 32; rr += 8) {
      uint2 kw[8];
#pragma unroll
      for (int q = 0; q < 8; ++q)          // 8 rows of loads in flight
        kw[q] = *reinterpret_cast<const uint2*>(Kw + (((size_t)(rr + q)) << 9));
#pragma unroll
      for (int q = 0; q < 8; ++q) {
        f32x2 p01 = __builtin_amdgcn_cvt_pk_f32_fp8(kw[q].x, false);
        f32x2 p23 = __builtin_amdgcn_cvt_pk_f32_fp8(kw[q].x, true);
        f32x2 p45 = __builtin_amdgcn_cvt_pk_f32_fp8(kw[q].y, false);
        f32x2 p67 = __builtin_amdgcn_cvt_pk_f32_fp8(kw[q].y, true);
        f32x2 s2 = {0.f, 0.f};
        s2 = pkfma(p01, ev2[0], s2);
        s2 = pkfma(p23, ev2[1], s2);
        s2 = pkfma(p45, ev2[2], s2);
        s2 = pkfma(p67, ev2[3], s2);
        float s = s2.x + s2.y;
#pragma unroll
        for (int o = 32; o > 0; o >>= 1) s += __shfl_xor(s, o);
        const float eu = __fdividef(muv, s);          // = exp(10*u_new)
        if (it == MAX_IT - 1 && lane == 0)
          u[(n << 9) + (w << 5) + rr + q] = 0.1f * (logmu - __logf(s));
        f32x2 eu2 = { eu, eu };
        ca2[0] = pkfma(p01, eu2, ca2[0]);
        ca2[1] = pkfma(p23, eu2, ca2[1]);
        ca2[2] = pkfma(p45, eu2, ca2[2]);
        ca2[3] = pkfma(p67, eu2, ca2[3]);
      }
    }
    {
      f32x4 s0 = { ca2[0].x, ca2[0].y, ca2[1].x, ca2[1].y };
      f32x4 s1 = { ca2[2].x, ca2[2].y, ca2[3].x, ca2[3].y };
      *reinterpret_cast<f32x4*>(&cbuf[w][lane << 3])       = s0;
      *reinterpret_cast<f32x4*>(&cbuf[w][(lane << 3) + 4]) = s1;
    }
    __syncthreads();
    if (tid < P) {
      float sc = 0.f;
#pragma unroll
      for (int q = 0; q < 16; ++q) sc += cbuf[q][tid];
      evLDS[tid] = __fdividef(muv, sc);    // = exp(10*v_new)
      if (it == MAX_IT - 1)
        ws[WS_V + (n << 9) + tid] = 0.1f * (logmu - __logf(sc));
    }
    __syncthreads();
  }
}

// pi = exp((u_i + v_j - C)/eps), cost[n] += pi*C; C recomputed (R8-proven)
__global__ __launch_bounds__(256)
void pi_kernel(const float* __restrict__ x, const float* __restrict__ y,
               const float* __restrict__ ws,
               float* __restrict__ pi, float* __restrict__ cost) {
  const int tid  = threadIdx.x;
  const int lane = tid & 63;
  const int wid  = tid >> 6;
  const int rowg = blockIdx.x * 4 + wid;
  const int n    = rowg >> 9;
  const int i    = rowg & (P - 1);

  __shared__ float ys[P * 3];
  {
    const float* yb = y + (size_t)(n << 9) * 3;
    for (int q = tid; q < P * 3; q += 256) ys[q] = yb[q];
  }
  __syncthreads();

  const int c0 = lane << 3;
  const float* xp = x + (size_t)rowg * 3;
  const float x0 = xp[0], x1 = xp[1], x2 = xp[2];
  const float uu = ws[WS_U + rowg];
  const float* vp = ws + WS_V + (n << 9) + c0;
  const float* Wr = ws + WS_W + i * P + c0;

  float acc = 0.f;
  float4 po[2];
#pragma unroll
  for (int h = 0; h < 2; ++h) {
    float4 v4 = *reinterpret_cast<const float4*>(vp + h * 4);
    float4 w4 = *reinterpret_cast<const float4*>(Wr + h * 4);
    float vv[4] = { v4.x, v4.y, v4.z, v4.w };
    float wv[4] = { w4.x, w4.y, w4.z, w4.w };
    float pq[4];
#pragma unroll
    for (int q = 0; q < 4; ++q) {
      const int j = c0 + h * 4 + q;
      float dx = x0 - ys[j * 3 + 0];
      float dy = x1 - ys[j * 3 + 1];
      float dz = x2 - ys[j * 3 + 2];
      dx = rintf(dx) - dx; dy = rintf(dy) - dy; dz = rintf(dz) - dz;
      float ds = dx * dx + dy * dy + dz * dz;
      float c  = ds * wv[q];
      float p  = __expf((uu + vv[q] - c) * 10.f);
      pq[q] = p;
      acc = fmaf(p, c, acc);
    }
    po[h] = make_float4(pq[0], pq[1], pq[2], pq[3]);
  }
  float* Pr = pi + ((size_t)rowg << 9) + c0;
  *reinterpret_cast<float4*>(Pr)     = po[0];
  *reinterpret_cast<float4*>(Pr + 4) = po[1];

#pragma unroll
  for (int o = 32; o > 0; o >>= 1) acc += __shfl_xor(acc, o);
  __shared__ float wsum[4];
  if (lane == 0) wsum[wid] = acc;
  __syncthreads();
  if (tid == 0) atomicAdd(cost + n, wsum[0] + wsum[1] + wsum[2] + wsum[3]);
}

extern "C" void kernel_launch(void* const* d_in, const int* in_sizes, int n_in,
                              void* d_out, int out_size, void* d_ws, size_t ws_size,
                              hipStream_t stream) {
  const float* x = (const float*)d_in[0];
  const float* y = (const float*)d_in[1];
  const float* species = (const float*)d_in[2];

  float* out  = (float*)d_out;
  float* cost = out;                     // 128
  float* pi   = out + 128;               // TOT
  float* C    = pi + (size_t)TOT;        // TOT
  float* dist = C + (size_t)TOT;         // TOT
  float* ws   = (float*)d_ws;

  hipLaunchKernelGGL(cmat2_kernel, dim3(TOT / 4 / 256), dim3(256), 0, stream,
                     x, y, species, C, dist, ws, cost);

  void* margs[] = { (void*)&ws };
  hipLaunchCooperativeKernel((void*)sink_m, dim3(512), dim3(512),
                             margs, 0, stream);

  hipLaunchKernelGGL(sink_g, dim3(NB), dim3(1024), 0, stream, ws);

  hipLaunchKernelGGL(pi_kernel, dim3(NB * P / 4), dim3(256), 0, stream,
                     x, y, ws, pi, cost);
}

// Round 16
// 1155.306 us; speedup vs baseline: 1.2530x; 1.2530x over previous
//
#include <hip/hip_runtime.h>

#define NB    128
#define P     512
#define PP    262144            // P*P
#define TOT   33554432          // NB*PP
#define MAX_IT 100

// d_ws layout (float offsets)
#define WS_W   0                // 262144 : |1/(s.s^T)+1e-5|
#define WS_U   262144           // 65536
#define WS_V   327680           // 65536
#define WS_K8  393216           // fp8[TOT] = 8388608 float slots

typedef float f32x2 __attribute__((ext_vector_type(2)));
typedef float f32x4 __attribute__((ext_vector_type(4)));

__device__ __forceinline__ f32x2 pkfma(f32x2 a, f32x2 b, f32x2 c) {
  f32x2 d;
  asm("v_pk_fma_f32 %0, %1, %2, %3" : "=v"(d) : "v"(a), "v"(b), "v"(c));
  return d;
}

// Fused prep+cmat (R15-proven): writes C, dist, K8 (OCP e4m3), W; zeros cost.
__global__ __launch_bounds__(256)
void cmat2_kernel(const float* __restrict__ x, const float* __restrict__ y,
                  const float* __restrict__ species,
                  float* __restrict__ C, float* __restrict__ dist,
                  float* __restrict__ ws, float* __restrict__ cost) {
  __shared__ float sp[P * 8];            // 16 KB: full species matrix
  const int tid = threadIdx.x;
  for (int q = tid; q < P * 8; q += 256) sp[q] = species[q];
  __syncthreads();

  const int g = blockIdx.x * 256 + tid;  // [0, TOT/4)
  const int base = g << 2;
  const int n = base >> 18;
  const int r = base & (PP - 1);
  const int i = r >> 9, j0 = r & (P - 1);
  const float* xp = x + ((n << 9) + i) * 3;
  const float x0 = xp[0], x1 = xp[1], x2 = xp[2];
  const float* yp = y + ((n << 9) + j0) * 3;
  const float* si = sp + i * 8;

  float c[4], d[4], wv[4], kf[4];
#pragma unroll
  for (int q = 0; q < 4; ++q) {
    const float* sj = sp + (j0 + q) * 8;
    float gd = 0.f;
#pragma unroll
    for (int k = 0; k < 8; ++k) gd = fmaf(si[k], sj[k], gd);
    const float w = fabsf(1.0f / gd + 1e-5f);
    wv[q] = w;
    float dx = x0 - yp[q * 3 + 0];
    float dy = x1 - yp[q * 3 + 1];
    float dz = x2 - yp[q * 3 + 2];
    dx = rintf(dx) - dx; dy = rintf(dy) - dy; dz = rintf(dz) - dz;
    const float ds = dx * dx + dy * dy + dz * dz;
    d[q] = ds;
    c[q] = ds * w;
    kf[q] = __expf(-10.f * c[q]);
  }

  f32x4 cv = { c[0], c[1], c[2], c[3] };
  f32x4 dv = { d[0], d[1], d[2], d[3] };
  *reinterpret_cast<f32x4*>(C + base)    = cv;
  *reinterpret_cast<f32x4*>(dist + base) = dv;

  int k8 = __builtin_amdgcn_cvt_pk_fp8_f32(kf[0], kf[1], 0, false);
  k8     = __builtin_amdgcn_cvt_pk_fp8_f32(kf[2], kf[3], k8, true);
  reinterpret_cast<int*>((unsigned char*)(ws + WS_K8))[g] = k8;

  if (n == 0) {                                        // store W once for pi
    f32x4 wv4 = { wv[0], wv[1], wv[2], wv[3] };
    *reinterpret_cast<f32x4*>(ws + WS_W + base) = wv4;
  }
  if (g < 32) {
    const f32x4 z4 = { 0.f, 0.f, 0.f, 0.f };
    *reinterpret_cast<f32x4*>(cost + (g << 2)) = z4;
  }
}

// ---- Sinkhorn: 128 blocks x 1024 threads, ONE block per batch, NO cross-
// block anything (no coop, no atomics, no fences — only __syncthreads, which
// is an inline s_barrier, so kreg survives in registers: no call boundary).
// K (fp8 e4m3) lives ENTIRELY in registers: 32 rows x 8 cols per thread =
// uint2 kreg[32] = 64 VGPRs. The 100-iter loop touches NO global memory.
// Wave w owns rows w*32..w*32+31; lane owns cols lane*8..lane*8+7.
__global__ __launch_bounds__(1024, 4)
void sink_r(float* __restrict__ ws) {
  const unsigned char* K8 = (const unsigned char*)(ws + WS_K8);
  float* u = ws + WS_U;

  const int tid  = threadIdx.x;
  const int lane = tid & 63;
  const int w    = tid >> 6;               // wave 0..15
  const int n    = blockIdx.x;             // batch

  __shared__ float evLDS[P];               // exp(10*v_j)
  __shared__ float cbuf[16][P];            // per-wave column partials (32 KB)

  if (tid < P) evLDS[tid] = 1.0f;          // v = 0
  __syncthreads();

  // Build: load this thread's K block once. Fully unrolled (const indices).
  const unsigned char* Kw = K8 + (((size_t)(n << 9) + (w << 5)) << 9) + (lane << 3);
  uint2 kreg[32];
#pragma unroll
  for (int r = 0; r < 32; ++r)
    kreg[r] = *reinterpret_cast<const uint2*>(Kw + ((size_t)r << 9));

  const float muv   = 1.0f / 512.0f + 1e-8f;
  const float logmu = logf(muv);

  for (int it = 0; it < MAX_IT; ++it) {
    f32x2 ev2[4], ca2[4];
#pragma unroll
    for (int t = 0; t < 4; ++t) {
      ev2[t] = *reinterpret_cast<const f32x2*>(&evLDS[(lane << 3) + (t << 1)]);
      ca2[t].x = 0.f; ca2[t].y = 0.f;
    }

#pragma unroll
    for (int r = 0; r < 32; ++r) {
      const uint2 kw = kreg[r];
      f32x2 p01 = __builtin_amdgcn_cvt_pk_f32_fp8(kw.x, false);
      f32x2 p23 = __builtin_amdgcn_cvt_pk_f32_fp8(kw.x, true);
      f32x2 p45 = __builtin_amdgcn_cvt_pk_f32_fp8(kw.y, false);
      f32x2 p67 = __builtin_amdgcn_cvt_pk_f32_fp8(kw.y, true);
      f32x2 s2 = {0.f, 0.f};
      s2 = pkfma(p01, ev2[0], s2);
      s2 = pkfma(p23, ev2[1], s2);
      s2 = pkfma(p45, ev2[2], s2);
      s2 = pkfma(p67, ev2[3], s2);
      float s = s2.x + s2.y;
#pragma unroll
      for (int o = 32; o > 0; o >>= 1) s += __shfl_xor(s, o);
      const float eu = __fdividef(muv, s);           // = exp(10*u_new)
      if (it == MAX_IT - 1 && lane == 0)             // u needed only at end
        u[(n << 9) + (w << 5) + r] = 0.1f * (logmu - __logf(s));
      f32x2 eu2 = { eu, eu };
      ca2[0] = pkfma(p01, eu2, ca2[0]);
      ca2[1] = pkfma(p23, eu2, ca2[1]);
      ca2[2] = pkfma(p45, eu2, ca2[2]);
      ca2[3] = pkfma(p67, eu2, ca2[3]);
    }
    {
      f32x4 s0 = { ca2[0].x, ca2[0].y, ca2[1].x, ca2[1].y };
      f32x4 s1 = { ca2[2].x, ca2[2].y, ca2[3].x, ca2[3].y };
      *reinterpret_cast<f32x4*>(&cbuf[w][lane << 3])       = s0;
      *reinterpret_cast<f32x4*>(&cbuf[w][(lane << 3) + 4]) = s1;
    }
    __syncthreads();
    if (tid < P) {
      float sc = 0.f;
#pragma unroll
      for (int q = 0; q < 16; ++q) sc += cbuf[q][tid];
      evLDS[tid] = __fdividef(muv, sc);    // = exp(10*v_new)
      if (it == MAX_IT - 1)
        ws[WS_V + (n << 9) + tid] = 0.1f * (logmu - __logf(sc));
    }
    __syncthreads();
  }
}

// pi = exp((u_i + v_j - C)/eps), cost[n] += pi*C; exact C recomputed (proven)
__global__ __launch_bounds__(256)
void pi_kernel(const float* __restrict__ x, const float* __restrict__ y,
               const float* __restrict__ ws,
               float* __restrict__ pi, float* __restrict__ cost) {
  const int tid  = threadIdx.x;
  const int lane = tid & 63;
  const int wid  = tid >> 6;
  const int rowg = blockIdx.x * 4 + wid;
  const int n    = rowg >> 9;
  const int i    = rowg & (P - 1);

  __shared__ float ys[P * 3];
  {
    const float* yb = y + (size_t)(n << 9) * 3;
    for (int q = tid; q < P * 3; q += 256) ys[q] = yb[q];
  }
  __syncthreads();

  const int c0 = lane << 3;
  const float* xp = x + (size_t)rowg * 3;
  const float x0 = xp[0], x1 = xp[1], x2 = xp[2];
  const float uu = ws[WS_U + rowg];
  const float* vp = ws + WS_V + (n << 9) + c0;
  const float* Wr = ws + WS_W + i * P + c0;

  float acc = 0.f;
  float4 po[2];
#pragma unroll
  for (int h = 0; h < 2; ++h) {
    float4 v4 = *reinterpret_cast<const float4*>(vp + h * 4);
    float4 w4 = *reinterpret_cast<const float4*>(Wr + h * 4);
    float vv[4] = { v4.x, v4.y, v4.z, v4.w };
    float wv[4] = { w4.x, w4.y, w4.z, w4.w };
    float pq[4];
#pragma unroll
    for (int q = 0; q < 4; ++q) {
      const int j = c0 + h * 4 + q;
      float dx = x0 - ys[j * 3 + 0];
      float dy = x1 - ys[j * 3 + 1];
      float dz = x2 - ys[j * 3 + 2];
      dx = rintf(dx) - dx; dy = rintf(dy) - dy; dz = rintf(dz) - dz;
      float ds = dx * dx + dy * dy + dz * dz;
      float c  = ds * wv[q];
      float p  = __expf((uu + vv[q] - c) * 10.f);
      pq[q] = p;
      acc = fmaf(p, c, acc);
    }
    po[h] = make_float4(pq[0], pq[1], pq[2], pq[3]);
  }
  float* Pr = pi + ((size_t)rowg << 9) + c0;
  *reinterpret_cast<float4*>(Pr)     = po[0];
  *reinterpret_cast<float4*>(Pr + 4) = po[1];

#pragma unroll
  for (int o = 32; o > 0; o >>= 1) acc += __shfl_xor(acc, o);
  __shared__ float wsum[4];
  if (lane == 0) wsum[wid] = acc;
  __syncthreads();
  if (tid == 0) atomicAdd(cost + n, wsum[0] + wsum[1] + wsum[2] + wsum[3]);
}

extern "C" void kernel_launch(void* const* d_in, const int* in_sizes, int n_in,
                              void* d_out, int out_size, void* d_ws, size_t ws_size,
                              hipStream_t stream) {
  const float* x = (const float*)d_in[0];
  const float* y = (const float*)d_in[1];
  const float* species = (const float*)d_in[2];

  float* out  = (float*)d_out;
  float* cost = out;                     // 128
  float* pi   = out + 128;               // TOT
  float* C    = pi + (size_t)TOT;        // TOT
  float* dist = C + (size_t)TOT;         // TOT
  float* ws   = (float*)d_ws;

  hipLaunchKernelGGL(cmat2_kernel, dim3(TOT / 4 / 256), dim3(256), 0, stream,
                     x, y, species, C, dist, ws, cost);

  hipLaunchKernelGGL(sink_r, dim3(NB), dim3(1024), 0, stream, ws);

  hipLaunchKernelGGL(pi_kernel, dim3(NB * P / 4), dim3(256), 0, stream,
                     x, y, ws, pi, cost);
}